// Round 11
// baseline (868.881 us; speedup 1.0000x reference)
//
#include <hip/hip_runtime.h>

#define NXc 256
#define NTc 256
#define NBLK 256          // 2 batches x 128 nodes (2 rows each)
#define DTv 0.0005f
#define INVD 0.2f

// ws float offsets
#define COEF_OFF 0        // 1024 floats
#define EX_OFF  1024      // byte 4096 (8B aligned): u64[2 par][256 blk][6 entry][256 col]
#define EX_ENT  6
#define EX_BLK  (EX_ENT*256)   // u64 per node slot
// entries: 0=syy[r0] 1=syy[r1] 2=sxy[r0] 3=sxy[r1] 4=sxx[r0] 5=sxx[r1]

__device__ __forceinline__ unsigned long long tld(const unsigned long long* p) {
  return __hip_atomic_load(p, __ATOMIC_RELAXED, __HIP_MEMORY_SCOPE_AGENT);
}
__device__ __forceinline__ void tst(unsigned long long* p, float v, unsigned tag) {
  unsigned long long u = ((unsigned long long)tag << 32) | (unsigned long long)__float_as_uint(v);
  __hip_atomic_store(p, u, __ATOMIC_RELAXED, __HIP_MEMORY_SCOPE_AGENT);
}
#define TVAL(x) __uint_as_float((unsigned)(x))
#define TTAG(x) ((unsigned)((x) >> 32))

__device__ __forceinline__ void bar_lds() {
  asm volatile("s_waitcnt lgkmcnt(0)" ::: "memory");
  __builtin_amdgcn_s_barrier();
  asm volatile("" ::: "memory");
}

__global__ __launch_bounds__(256) void setup_kernel(
    const float* __restrict__ lamb, const float* __restrict__ mu,
    const float* __restrict__ buoy, float* __restrict__ coef)
{
  __shared__ float red[256];
  const int tid = threadIdx.x;
  float m = 0.0f;
  for (int i = tid; i < 256*256; i += 256)
    m = fmaxf(m, sqrtf((lamb[i] + 2.0f*mu[i]) * buoy[i]));
  red[tid] = m;
  __syncthreads();
  for (int s = 128; s > 0; s >>= 1) {
    if (tid < s) red[tid] = fmaxf(red[tid], red[tid+s]);
    __syncthreads();
  }
  const float maxv = red[0];
  const float i_f = (float)tid;
  const float w = 20.0f;
  float f1 = fminf(fmaxf((w - i_f) * (1.0f/w), 0.0f), 1.0f);
  float f2 = fminf(fmaxf((i_f - (256.0f - 1.0f - w)) * (1.0f/w), 0.0f), 1.0f);
  float frac = fmaxf(f1, f2);
  float sigma_max = 3.0f * maxv * 6.907755278982137f / (2.0f * w * 5.0f);
  float sigma = sigma_max * frac * frac;
  float alpha = 3.14159265358979323f * 25.0f * (1.0f - frac);
  float bc = expf(-(sigma + alpha) * 0.0005f);
  float ac = sigma / (sigma + alpha + 1e-9f) * (bc - 1.0f);
  coef[tid]       = ac;  // ay
  coef[256 + tid] = bc;  // by
  coef[512 + tid] = ac;  // ax
  coef[768 + tid] = bc;  // bx
}

__global__ __launch_bounds__(256) void elastic_n2(
    const float* __restrict__ lamb_g, const float* __restrict__ mu_g,
    const float* __restrict__ buoy_g, const float* __restrict__ amps,
    const int* __restrict__ src_loc, const int* __restrict__ rec_loc,
    float* __restrict__ ws, float* __restrict__ out)
{
  // tiny LDS: wave-boundary column exchange (writer wave indexed)
  __shared__ float SxyB[4][2], SxxB[4][2], VyB[4][2], VxB[4][2];

  const int blk = blockIdx.x;
  const int b = blk >> 7, n = blk & 127;
  const int tx = threadIdx.x;            // column
  const int lane = tx & 63, wv = tx >> 6;
  const int lo = n << 1;                 // own rows lo, lo+1
  const bool hasUp = n > 0, hasDn = n < 127;
  const bool xm_ok = tx > 0, xp_ok = tx < 255;

  const float* coef = ws + COEF_OFF;
  unsigned long long* exb = (unsigned long long*)(ws + EX_OFF);

  const float axv = coef[512+tx], bxv = coef[768+tx];

  // per-row coefficients: U=lo-1, 0=lo, 1=lo+1, D=lo+2
  const float ayU = hasUp ? coef[lo-1] : 0.f;
  const float byU = hasUp ? coef[256+lo-1] : 1.f;
  const float dtbU = hasUp ? DTv*buoy_g[(lo-1)*NXc+tx] : 0.f;
  const float ay0 = coef[lo],   by0 = coef[256+lo];
  const float dtb0 = DTv*buoy_g[lo*NXc+tx];
  const float ay1 = coef[lo+1], by1 = coef[256+lo+1];
  const float dtb1 = DTv*buoy_g[(lo+1)*NXc+tx];
  const float ayD = hasDn ? coef[lo+2] : 0.f;
  const float byD = hasDn ? coef[256+lo+2] : 1.f;
  const float dtbD = hasDn ? DTv*buoy_g[(lo+2)*NXc+tx] : 0.f;
  const float lam0 = lamb_g[lo*NXc+tx],     mu0 = mu_g[lo*NXc+tx],     l2m0 = lam0+2.f*mu0;
  const float lam1 = lamb_g[(lo+1)*NXc+tx], mu1 = mu_g[(lo+1)*NXc+tx], l2m1 = lam1+2.f*mu1;

  // state: own V rows lo,lo+1 + replicas lo-1,lo+2 ; own S rows lo,lo+1
  float vy0=0,vy1=0,vx0=0,vx1=0, vyU=0,vxU=0, vyD=0,vxD=0;
  float myy0=0,myy1=0,myx0=0,myx1=0,mxyy0=0,mxyy1=0,mxx0=0,mxx1=0;
  float myyU=0,myxU=0,mxyyU=0,mxxU=0, myyD=0,myxD=0,mxyyD=0,mxxD=0;
  float syy0=0,syy1=0,sxy0=0,sxy1=0,sxx0=0,sxx1=0;
  float mvyy0=0,mvyy1=0,mvxx0=0,mvxx1=0,mvyx0=0,mvyx1=0,mvxy0=0,mvxy1=0;

  // sources: v-rows lo-1..lo+2 -> slot r = sy-(lo-1) in [0,4)
  int sk0=-1, sk1=-1, so0=0, so1=0;
  for (int i = 0; i < 4; ++i) {
    const int sb = i >> 1, sy = src_loc[2*i], sx = src_loc[2*i+1];
    if (sb == b && sx == tx) {
      const int r = sy - (lo - 1);
      if (r >= 0 && r < 4) { if (sk0 < 0) { sk0=r; so0=i*NTc; } else { sk1=r; so1=i*NTc; } }
    }
  }
  // receivers: own rows lo (vy0) and lo+1 (vy1)
  unsigned long long rA0=0,rA1=0,rB0=0,rB1=0;
  for (int i = 0; i < 128; ++i) {
    const int rb = i >> 6, ry = rec_loc[2*i], rx = rec_loc[2*i+1];
    if (rb == b && rx == tx) {
      const unsigned long long bit = 1ull << (i & 63);
      if (ry == lo)   { if (i<64) rA0|=bit; else rA1|=bit; }
      if (ry == lo+1) { if (i<64) rB0|=bit; else rB1|=bit; }
    }
  }
  const bool recA = (rA0|rA1)!=0ull, recB = (rB0|rB1)!=0ull;

  if (tx < 8) {
    SxyB[tx>>1][tx&1]=0.f; SxxB[tx>>1][tx&1]=0.f;
    VyB[tx>>1][tx&1]=0.f;  VxB[tx>>1][tx&1]=0.f;
  }
  __syncthreads();

  for (int t = 0; t < NTc; ++t) {
    float a0=0.f, a1=0.f;
    if (sk0>=0) a0 = amps[so0+t];
    if (sk1>=0) a1 = amps[so1+t];

    // ========== tagged poll+ingest (t=0 passes on zeroed slot 1) ==========
    const size_t ps = (size_t)((t+1)&1)*NBLK;
    const unsigned long long* up = exb + (ps + (size_t)(hasUp?blk-1:blk))*EX_BLK + tx;
    const unsigned long long* dn = exb + (ps + (size_t)(hasDn?blk+1:blk))*EX_BLK + tx;
    const unsigned want = (unsigned)t;
    unsigned long long u0=0,u1=0,u3=0,u5=0,u3m=0,u5p=0;
    unsigned long long d0=0,d2=0,d3=0,d4=0,d2m=0,d4p=0;
    for (;;) {
      bool ok = true;
      if (hasUp) {
        u0=tld(up+0*256); u1=tld(up+1*256); u3=tld(up+3*256); u5=tld(up+5*256);
        ok = ok && TTAG(u0)==want && TTAG(u1)==want && TTAG(u3)==want && TTAG(u5)==want;
        if (lane==0 && xm_ok)  { u3m=tld(up+3*256-1); ok = ok && TTAG(u3m)==want; }
        if (lane==63 && xp_ok) { u5p=tld(up+5*256+1); ok = ok && TTAG(u5p)==want; }
      }
      if (hasDn) {
        d0=tld(dn+0*256); d2=tld(dn+2*256); d3=tld(dn+3*256); d4=tld(dn+4*256);
        ok = ok && TTAG(d0)==want && TTAG(d2)==want && TTAG(d3)==want && TTAG(d4)==want;
        if (lane==0 && xm_ok)  { d2m=tld(dn+2*256-1); ok = ok && TTAG(d2m)==want; }
        if (lane==63 && xp_ok) { d4p=tld(dn+4*256+1); ok = ok && TTAG(d4p)==want; }
      }
      if (ok) break;
    }
    const float syyU0=TVAL(u0), syyU1=TVAL(u1), sxyU1=TVAL(u3), sxxU1=TVAL(u5);
    const float syyD0=TVAL(d0), sxyD0=TVAL(d2), sxyD1=TVAL(d3), sxxD0=TVAL(d4);
    const float sxyU1m=TVAL(u3m), sxxU1p=TVAL(u5p);
    const float sxyD0m=TVAL(d2m), sxxD0p=TVAL(d4p);

    // ========== A: velocity (y in regs, x by shuffle) ==========
    // r=U: row lo-1 (replica, bitwise-identical to up-node's own row 1)
    if (hasUp) {
      float d,t1,t2,t3,t4;
      d = (syyU1 - syyU0) * INVD;                       // dby; gy=lo-1>=1
      myyU = byU*myyU + ayU*d; t1 = d + myyU;
      float sm = __shfl_up(sxyU1, 1, 64); if (lane==0) sm = sxyU1m;
      d = xm_ok ? (sxyU1 - sm) * INVD : 0.f;
      myxU = bxv*myxU + axv*d; t2 = d + myxU;
      vyU += dtbU*(t1+t2);
      d = (sxy0 - sxyU1) * INVD;                        // dfy; gy<=253
      mxyyU = byU*mxyyU + ayU*d; t3 = d + mxyyU;
      float sp = __shfl_down(sxxU1, 1, 64); if (lane==63) sp = sxxU1p;
      d = xp_ok ? (sp - sxxU1) * INVD : 0.f;
      mxxU = bxv*mxxU + axv*d; t4 = d + mxxU;
      vxU += dtbU*(t3+t4);
      if (sk0==0) vyU += a0*dtbU;
      if (sk1==0) vyU += a1*dtbU;
    }
    // r=0: row lo (own)
    {
      float d,t1,t2,t3,t4;
      d = hasUp ? (syy0 - syyU1) * INVD : 0.f;          // dby; gy=0 only n=0
      myy0 = by0*myy0 + ay0*d; t1 = d + myy0;
      float sm = __shfl_up(sxy0, 1, 64); if (lane==0 && wv>0) sm = SxyB[wv-1][0];
      d = xm_ok ? (sxy0 - sm) * INVD : 0.f;
      myx0 = bxv*myx0 + axv*d; t2 = d + myx0;
      vy0 += dtb0*(t1+t2);
      d = (sxy1 - sxy0) * INVD;                         // dfy; gy=lo<=254
      mxyy0 = by0*mxyy0 + ay0*d; t3 = d + mxyy0;
      float sp = __shfl_down(sxx0, 1, 64); if (lane==63 && wv<3) sp = SxxB[wv+1][0];
      d = xp_ok ? (sp - sxx0) * INVD : 0.f;
      mxx0 = bxv*mxx0 + axv*d; t4 = d + mxx0;
      vx0 += dtb0*(t3+t4);
      if (sk0==1) vy0 += a0*dtb0;
      if (sk1==1) vy0 += a1*dtb0;
    }
    // r=1: row lo+1 (own)
    {
      float d,t1,t2,t3,t4;
      d = (syy1 - syy0) * INVD;                         // dby; gy>=1
      myy1 = by1*myy1 + ay1*d; t1 = d + myy1;
      float sm = __shfl_up(sxy1, 1, 64); if (lane==0 && wv>0) sm = SxyB[wv-1][1];
      d = xm_ok ? (sxy1 - sm) * INVD : 0.f;
      myx1 = bxv*myx1 + axv*d; t2 = d + myx1;
      vy1 += dtb1*(t1+t2);
      d = hasDn ? (sxyD0 - sxy1) * INVD : 0.f;          // dfy; gy=255 only n=127
      mxyy1 = by1*mxyy1 + ay1*d; t3 = d + mxyy1;
      float sp = __shfl_down(sxx1, 1, 64); if (lane==63 && wv<3) sp = SxxB[wv+1][1];
      d = xp_ok ? (sp - sxx1) * INVD : 0.f;
      mxx1 = bxv*mxx1 + axv*d; t4 = d + mxx1;
      vx1 += dtb1*(t3+t4);
      if (sk0==2) vy1 += a0*dtb1;
      if (sk1==2) vy1 += a1*dtb1;
    }
    // r=D: row lo+2 (replica of down-node's own row 0)
    if (hasDn) {
      float d,t1,t2,t3,t4;
      d = (syyD0 - syy1) * INVD;                        // dby; gy=lo+2>=2
      myyD = byD*myyD + ayD*d; t1 = d + myyD;
      float sm = __shfl_up(sxyD0, 1, 64); if (lane==0) sm = sxyD0m;
      d = xm_ok ? (sxyD0 - sm) * INVD : 0.f;
      myxD = bxv*myxD + axv*d; t2 = d + myxD;
      vyD += dtbD*(t1+t2);
      d = (sxyD1 - sxyD0) * INVD;                       // dfy; gy=lo+2<=254
      mxyyD = byD*mxyyD + ayD*d; t3 = d + mxyyD;
      float sp = __shfl_down(sxxD0, 1, 64); if (lane==63) sp = sxxD0p;
      d = xp_ok ? (sp - sxxD0) * INVD : 0.f;
      mxxD = bxv*mxxD + axv*d; t4 = d + mxxD;
      vxD += dtbD*(t3+t4);
      if (sk0==3) vyD += a0*dtbD;
      if (sk1==3) vyD += a1*dtbD;
    }

    // wave-boundary V exchange + recording (stores don't block the LDS barrier)
    if (lane == 63) { VyB[wv][0]=vy0; VyB[wv][1]=vy1; VxB[wv][0]=vx0; VxB[wv][1]=vx1; }
    if (recA) {
      unsigned long long m;
      m=rA0; while(m){int i=__ffsll((long long)m)-1;m&=m-1;out[i*NTc+t]=vy0;}
      m=rA1; while(m){int i=__ffsll((long long)m)-1;m&=m-1;out[(i+64)*NTc+t]=vy0;}
    }
    if (recB) {
      unsigned long long m;
      m=rB0; while(m){int i=__ffsll((long long)m)-1;m&=m-1;out[i*NTc+t]=vy1;}
      m=rB1; while(m){int i=__ffsll((long long)m)-1;m&=m-1;out[(i+64)*NTc+t]=vy1;}
    }
    bar_lds();

    // ========== B: stress on own rows; ship ASAP ==========
    unsigned long long* Q = exb + ((size_t)(t&1)*NBLK + blk)*EX_BLK + tx;
    const unsigned wt = (unsigned)(t+1);
    {
      float vym = __shfl_up(vy0, 1, 64); if (lane==0 && wv>0) vym = VyB[wv-1][0];
      float vxm = __shfl_up(vx0, 1, 64); if (lane==0 && wv>0) vxm = VxB[wv-1][0];
      float d,u5,u6,u7,u8;
      d = (vy1 - vy0) * INVD;                           // dfy; gy=lo<=254
      mvyy0 = by0*mvyy0 + ay0*d; u5 = d + mvyy0;
      d = xm_ok ? (vx0 - vxm) * INVD : 0.f;
      mvxx0 = bxv*mvxx0 + axv*d; u6 = d + mvxx0;
      syy0 += DTv*(l2m0*u5 + lam0*u6);
      sxx0 += DTv*(lam0*u5 + l2m0*u6);
      d = xm_ok ? (vy0 - vym) * INVD : 0.f;
      mvyx0 = bxv*mvyx0 + axv*d; u7 = d + mvyx0;
      d = hasUp ? (vx0 - vxU) * INVD : 0.f;             // dby; gy=0 only n=0
      mvxy0 = by0*mvxy0 + ay0*d; u8 = d + mvxy0;
      sxy0 += DTv*mu0*(u7+u8);
      tst(Q+0*256, syy0, wt); tst(Q+2*256, sxy0, wt); tst(Q+4*256, sxx0, wt);
    }
    {
      float vym = __shfl_up(vy1, 1, 64); if (lane==0 && wv>0) vym = VyB[wv-1][1];
      float vxm = __shfl_up(vx1, 1, 64); if (lane==0 && wv>0) vxm = VxB[wv-1][1];
      float d,u5,u6,u7,u8;
      d = hasDn ? (vyD - vy1) * INVD : 0.f;             // dfy; gy=255 only n=127
      mvyy1 = by1*mvyy1 + ay1*d; u5 = d + mvyy1;
      d = xm_ok ? (vx1 - vxm) * INVD : 0.f;
      mvxx1 = bxv*mvxx1 + axv*d; u6 = d + mvxx1;
      syy1 += DTv*(l2m1*u5 + lam1*u6);
      sxx1 += DTv*(lam1*u5 + l2m1*u6);
      d = xm_ok ? (vy1 - vym) * INVD : 0.f;
      mvyx1 = bxv*mvyx1 + axv*d; u7 = d + mvyx1;
      d = (vx1 - vx0) * INVD;                           // dby; gy=lo+1>=1
      mvxy1 = by1*mvxy1 + ay1*d; u8 = d + mvxy1;
      sxy1 += DTv*mu1*(u7+u8);
      tst(Q+1*256, syy1, wt); tst(Q+3*256, sxy1, wt); tst(Q+5*256, sxx1, wt);
    }
    // wave-boundary S exchange for next step's A
    if (lane == 63) { SxyB[wv][0]=sxy0; SxyB[wv][1]=sxy1; }
    if (lane == 0)  { SxxB[wv][0]=sxx0; SxxB[wv][1]=sxx1; }
    bar_lds();
  }
}

extern "C" void kernel_launch(void* const* d_in, const int* in_sizes, int n_in,
                              void* d_out, int out_size, void* d_ws, size_t ws_size,
                              hipStream_t stream) {
  const float* lamb    = (const float*)d_in[0];
  const float* mu      = (const float*)d_in[1];
  const float* buoy    = (const float*)d_in[2];
  const float* amps    = (const float*)d_in[3];
  const int*   src_loc = (const int*)d_in[4];
  const int*   rec_loc = (const int*)d_in[5];
  float* out = (float*)d_out;
  float* ws  = (float*)d_ws;

  // tag region must start at 0 every launch (tags 1..256 within one run)
  hipMemsetAsync((char*)ws + EX_OFF*sizeof(float), 0,
                 (size_t)2*NBLK*EX_BLK*sizeof(unsigned long long), stream);

  hipLaunchKernelGGL(setup_kernel, dim3(1), dim3(256), 0, stream,
                     lamb, mu, buoy, ws + COEF_OFF);

  void* args[] = { (void*)&lamb, (void*)&mu, (void*)&buoy, (void*)&amps,
                   (void*)&src_loc, (void*)&rec_loc, (void*)&ws, (void*)&out };
  hipLaunchCooperativeKernel((void*)elastic_n2, dim3(NBLK), dim3(256),
                             args, 0, stream);
}